// Round 1
// baseline (552.908 us; speedup 1.0000x reference)
//
#include <hip/hip_runtime.h>
#include <cmath>

typedef __attribute__((ext_vector_type(4))) float f32x4;
typedef __attribute__((ext_vector_type(8))) __bf16 bf16x8;
typedef __attribute__((ext_vector_type(8))) unsigned short u16x8;
typedef __attribute__((ext_vector_type(4))) unsigned short u16x4;

#define DEV __device__ __forceinline__

DEV unsigned short f2b(float v) {
  __bf16 b = (__bf16)v;
  return __builtin_bit_cast(unsigned short, b);
}

// async global->LDS, 16B per lane. lds ptr must be wave-uniform; HW writes
// lane l at lds + l*16. AS casts via integer round-trip (generic LDS ptr's
// low 32 bits == LDS offset on amdgcn).
DEV void gll16(const void* g, const void* l) {
  __builtin_amdgcn_global_load_lds(
      (const __attribute__((address_space(1))) unsigned int*)(unsigned long long)g,
      (__attribute__((address_space(3))) unsigned int*)(unsigned int)(unsigned long long)l,
      16, 0, 0);
}

// ---------------- fp32 -> bf16 convert (weights) ----------------
__global__ void k_cvt_bf16(const float* __restrict__ src,
                           unsigned short* __restrict__ dst, int n4) {
  int i = blockIdx.x * blockDim.x + threadIdx.x;
  if (i >= n4) return;
  float4 v = ((const float4*)src)[i];
  u16x4 o = {f2b(v.x), f2b(v.y), f2b(v.z), f2b(v.w)};
  *(u16x4*)(dst + (size_t)i * 4) = o;
}

// ---------------- LayerNorm: fp32 [row][768] -> bf16 ----------------
// one wave per row; lane handles 3 float4 (12 elems)
__global__ void k_ln(const float* __restrict__ x, const float* __restrict__ g,
                     const float* __restrict__ be, unsigned short* __restrict__ out) {
  int row = blockIdx.x;
  int l = threadIdx.x;  // 0..63
  const float* xr = x + (size_t)row * 768;
  float4 v[3];
  float s = 0.f, sq = 0.f;
#pragma unroll
  for (int j = 0; j < 3; ++j) {
    v[j] = ((const float4*)xr)[l + 64 * j];
    s += v[j].x + v[j].y + v[j].z + v[j].w;
    sq += v[j].x * v[j].x + v[j].y * v[j].y + v[j].z * v[j].z + v[j].w * v[j].w;
  }
#pragma unroll
  for (int m = 1; m < 64; m <<= 1) {
    s += __shfl_xor(s, m);
    sq += __shfl_xor(sq, m);
  }
  float mu = s * (1.f / 768.f);
  float var = sq * (1.f / 768.f) - mu * mu;
  float rs = rsqrtf(var + 1e-6f);
  unsigned short* orow = out + (size_t)row * 768;
#pragma unroll
  for (int j = 0; j < 3; ++j) {
    int c4 = l + 64 * j;
    float4 gv = ((const float4*)g)[c4];
    float4 bv = ((const float4*)be)[c4];
    u16x4 o = {f2b((v[j].x - mu) * rs * gv.x + bv.x),
               f2b((v[j].y - mu) * rs * gv.y + bv.y),
               f2b((v[j].z - mu) * rs * gv.z + bv.z),
               f2b((v[j].w - mu) * rs * gv.w + bv.w)};
    *(u16x4*)(orow + c4 * 4) = o;
  }
}

// ---------------- GEMM: C[M,N] = A[M,K](bf16) @ B[N,K]^T(bf16) ----------------
// m97 structure: 128x128 tile, BK=32, 4 waves (2x2), 16 MFMA 16x16x32/K-step,
// global_load_lds width=16 staging.
// MODE 0: out bf16 = acc+bias          (QKV)
// MODE 1: out f32  = acc+bias+res      (proj + residual -> x1)
// MODE 2: out bf16 = gelu(acc+bias)    (MLP1, exact erf gelu)
// MODE 3: out f32  = acc+bias+res      (MLP2 + residual -> d_out)
template <int MODE>
__global__ __launch_bounds__(256) void k_gemm(
    const unsigned short* __restrict__ A, const unsigned short* __restrict__ Bw,
    const float* __restrict__ bias, const float* __restrict__ res,
    void* __restrict__ outp, int N, int K) {
  __shared__ unsigned short As[128 * 32];
  __shared__ unsigned short Bs[128 * 32];
  const int tid = threadIdx.x;
  const int w = tid >> 6, l = tid & 63;
  const int wr = w >> 1, wc = w & 1;
  const int lr = l & 15, lg = l >> 4;
  const int brow = blockIdx.y * 128, bcol = blockIdx.x * 128;
  f32x4 acc[4][4] = {};
  for (int kt = 0; kt < K; kt += 32) {
    __syncthreads();  // prev iter's LDS reads done before overwrite
#pragma unroll
    for (int i = 0; i < 2; ++i) {
      int c = i * 256 + tid;
      gll16(A + (size_t)(brow + (c >> 2)) * K + kt + (c & 3) * 8,
            (const char*)As + (i * 256 + (w << 6)) * 16);
      gll16(Bw + (size_t)(bcol + (c >> 2)) * K + kt + (c & 3) * 8,
            (const char*)Bs + (i * 256 + (w << 6)) * 16);
    }
    asm volatile("s_waitcnt vmcnt(0)" ::: "memory");
    __syncthreads();
    bf16x8 af[4], bfr[4];
#pragma unroll
    for (int m = 0; m < 4; ++m)
      af[m] = *(const bf16x8*)&As[(wr * 64 + m * 16 + lr) * 32 + lg * 8];
#pragma unroll
    for (int n = 0; n < 4; ++n)
      bfr[n] = *(const bf16x8*)&Bs[(wc * 64 + n * 16 + lr) * 32 + lg * 8];
#pragma unroll
    for (int m = 0; m < 4; ++m)
#pragma unroll
      for (int n = 0; n < 4; ++n)
        acc[m][n] = __builtin_amdgcn_mfma_f32_16x16x32_bf16(af[m], bfr[n], acc[m][n], 0, 0, 0);
  }
  // epilogue: C/D layout col=lane&15, row=(lane>>4)*4+reg (m89-verified)
#pragma unroll
  for (int n = 0; n < 4; ++n) {
    int col = bcol + wc * 64 + n * 16 + lr;
    float bv = bias[col];
#pragma unroll
    for (int m = 0; m < 4; ++m) {
      int row0 = brow + wr * 64 + m * 16 + lg * 4;
#pragma unroll
      for (int r = 0; r < 4; ++r) {
        size_t idx = (size_t)(row0 + r) * N + col;
        float v = acc[m][n][r] + bv;
        if (MODE == 0) {
          ((unsigned short*)outp)[idx] = f2b(v);
        } else if (MODE == 1) {
          ((float*)outp)[idx] = v + res[idx];
        } else if (MODE == 2) {
          ((unsigned short*)outp)[idx] = f2b(0.5f * v * (1.f + erff(v * 0.70710678f)));
        } else {
          ((float*)outp)[idx] = v + res[idx];
        }
      }
    }
  }
}

// ---------------- fused attention (flash-style, non-causal) ----------------
// grid: 24 (b,h) * 32 q-tiles. block = 4 waves; each wave owns 32 q rows.
// swapped QK^T: S^T = K @ Q^T so per-lane q = lane&15 (+16*qf); softmax state
// per-lane, 2 shuffles per reduce. K, V reg-staged to padded LDS (stride 72
// elems = 144B -> 2-way bank conflicts, free). V stored transposed so PV
// B-frags are contiguous ds_read_b128.
__global__ __launch_bounds__(256) void k_attn(const unsigned short* __restrict__ qkv,
                                              unsigned short* __restrict__ out) {
  __shared__ unsigned short Ks[64 * 72];      // K[key][hd], padded
  __shared__ unsigned short Vt[64 * 72];      // V^T[hd][key], padded
  __shared__ unsigned short Ps[4][32 * 72];   // per-wave P[q][key], padded
  const int tid = threadIdx.x;
  const int w = tid >> 6, l = tid & 63, lr = l & 15, lg = l >> 4;
  const int bh = blockIdx.x >> 5, qt = blockIdx.x & 31;
  const int b = bh / 12, h = bh % 12;
  const size_t base = (size_t)b * 4096 * 2304;
  const int qbase = qt * 128 + w * 32;
  const float scale = 0.125f;  // HD^-0.5

  // Q as B-frags of S^T = K@Q^T: lane holds q=lr, hd = lg*8..+8 (+32*ks)
  bf16x8 qb[2][2];
#pragma unroll
  for (int qf = 0; qf < 2; ++qf)
#pragma unroll
    for (int ks = 0; ks < 2; ++ks)
      qb[qf][ks] = *(const bf16x8*)(qkv + base + (size_t)(qbase + qf * 16 + lr) * 2304 +
                                    h * 64 + ks * 32 + lg * 8);

  f32x4 O[2][4] = {};
  float mrun[2] = {-INFINITY, -INFINITY};
  float lrun[2] = {0.f, 0.f};

  for (int kv = 0; kv < 4096; kv += 64) {
    // stage K/V tile: global->reg (overlaps barrier wait), then reg->LDS
    u16x8 kc[2], vc[2];
#pragma unroll
    for (int i = 0; i < 2; ++i) {
      int c = i * 256 + tid;
      int key = c >> 3, hd8 = (c & 7) * 8;
      const unsigned short* src = qkv + base + (size_t)(kv + key) * 2304 + h * 64 + hd8;
      kc[i] = *(const u16x8*)(src + 768);    // K block
      vc[i] = *(const u16x8*)(src + 1536);   // V block
    }
    __syncthreads();  // all waves done reading prev tile
#pragma unroll
    for (int i = 0; i < 2; ++i) {
      int c = i * 256 + tid;
      int key = c >> 3, hd8 = (c & 7) * 8;
      *(u16x8*)&Ks[key * 72 + hd8] = kc[i];
#pragma unroll
      for (int j = 0; j < 8; ++j) Vt[(hd8 + j) * 72 + key] = vc[i][j];
    }
    __syncthreads();

    // S^T = K @ Q^T : frag (kf,qf): col=q=lr, row=key=kf*16+lg*4+r
    f32x4 st[4][2] = {};
#pragma unroll
    for (int kf = 0; kf < 4; ++kf)
#pragma unroll
      for (int ks = 0; ks < 2; ++ks) {
        bf16x8 ka = *(const bf16x8*)&Ks[(kf * 16 + lr) * 72 + ks * 32 + lg * 8];
#pragma unroll
        for (int qf = 0; qf < 2; ++qf)
          st[kf][qf] = __builtin_amdgcn_mfma_f32_16x16x32_bf16(ka, qb[qf][ks], st[kf][qf], 0, 0, 0);
      }

    // online softmax; lane's q = qf*16 + lr
#pragma unroll
    for (int qf = 0; qf < 2; ++qf) {
      float mloc = -INFINITY;
#pragma unroll
      for (int kf = 0; kf < 4; ++kf)
#pragma unroll
        for (int r = 0; r < 4; ++r) mloc = fmaxf(mloc, st[kf][qf][r]);
      mloc = fmaxf(mloc, __shfl_xor(mloc, 16));
      mloc = fmaxf(mloc, __shfl_xor(mloc, 32));
      float mnew = fmaxf(mrun[qf], mloc);
      float alpha = __expf((mrun[qf] - mnew) * scale);
      float ssum = 0.f;
#pragma unroll
      for (int kf = 0; kf < 4; ++kf)
#pragma unroll
        for (int r = 0; r < 4; ++r) {
          float p = __expf((st[kf][qf][r] - mnew) * scale);
          ssum += p;
          Ps[w][(qf * 16 + lr) * 72 + kf * 16 + lg * 4 + r] = f2b(p);
        }
      ssum += __shfl_xor(ssum, 16);
      ssum += __shfl_xor(ssum, 32);
      lrun[qf] = lrun[qf] * alpha + ssum;
      mrun[qf] = mnew;
      // rescale O: O-frag row q' = lg*4+r; alpha for q' lives in lane q'
#pragma unroll
      for (int r = 0; r < 4; ++r) {
        float aT = __shfl(alpha, lg * 4 + r);
#pragma unroll
        for (int hf = 0; hf < 4; ++hf) O[qf][hf][r] *= aT;
      }
    }

    // PV: O[q][hd] += P @ V
#pragma unroll
    for (int ks = 0; ks < 2; ++ks) {
      bf16x8 pa[2], vb[4];
#pragma unroll
      for (int qf = 0; qf < 2; ++qf)
        pa[qf] = *(const bf16x8*)&Ps[w][(qf * 16 + lr) * 72 + ks * 32 + lg * 8];
#pragma unroll
      for (int hf = 0; hf < 4; ++hf)
        vb[hf] = *(const bf16x8*)&Vt[(hf * 16 + lr) * 72 + ks * 32 + lg * 8];
#pragma unroll
      for (int qf = 0; qf < 2; ++qf)
#pragma unroll
        for (int hf = 0; hf < 4; ++hf)
          O[qf][hf] = __builtin_amdgcn_mfma_f32_16x16x32_bf16(pa[qf], vb[hf], O[qf][hf], 0, 0, 0);
    }
  }

  // epilogue: divide by l, write bf16 [b,t,h*64+hd]
#pragma unroll
  for (int qf = 0; qf < 2; ++qf)
#pragma unroll
    for (int r = 0; r < 4; ++r) {
      float lT = __shfl(lrun[qf], lg * 4 + r);
      float rl = 1.f / lT;
      int t = qbase + qf * 16 + lg * 4 + r;
#pragma unroll
      for (int hf = 0; hf < 4; ++hf)
        out[(size_t)(b * 4096 + t) * 768 + h * 64 + hf * 16 + lr] = f2b(O[qf][hf][r] * rl);
    }
}

// ---------------- launch ----------------
extern "C" void kernel_launch(void* const* d_in, const int* in_sizes, int n_in,
                              void* d_out, int out_size, void* d_ws, size_t ws_size,
                              hipStream_t stream) {
  const float* x = (const float*)d_in[0];
  const float* Wqkv = (const float*)d_in[1];
  const float* bqkv = (const float*)d_in[2];
  const float* Wproj = (const float*)d_in[3];
  const float* bproj = (const float*)d_in[4];
  const float* W1 = (const float*)d_in[5];
  const float* b1 = (const float*)d_in[6];
  const float* W2 = (const float*)d_in[7];
  const float* b2 = (const float*)d_in[8];
  const float* g1 = (const float*)d_in[9];
  const float* be1 = (const float*)d_in[10];
  const float* g2 = (const float*)d_in[11];
  const float* be2 = (const float*)d_in[12];

  char* ws = (char*)d_ws;
  unsigned short* wqkv = (unsigned short*)(ws + 0);          //  3,538,944 B
  unsigned short* wproj = (unsigned short*)(ws + 3538944);   //  1,179,648
  unsigned short* ww1 = (unsigned short*)(ws + 4718592);     //  4,718,592
  unsigned short* ww2 = (unsigned short*)(ws + 9437184);     //  4,718,592
  unsigned short* h1 = (unsigned short*)(ws + 14155776);     // 12,582,912
  unsigned short* qkvb = (unsigned short*)(ws + 26738688);   // 37,748,736
  unsigned short* attno = (unsigned short*)(ws + 64487424);  // 12,582,912
  float* x1 = (float*)(ws + 77070336);                       // 25,165,824
  unsigned short* h2 = (unsigned short*)(ws + 102236160);    // 12,582,912
  unsigned short* m1 = (unsigned short*)(ws + 114819072);    // 50,331,648  (end 165,150,720)

  // weights -> bf16
  k_cvt_bf16<<<1728, 256, 0, stream>>>(Wqkv, wqkv, 442368);
  k_cvt_bf16<<<576, 256, 0, stream>>>(Wproj, wproj, 147456);
  k_cvt_bf16<<<2304, 256, 0, stream>>>(W1, ww1, 589824);
  k_cvt_bf16<<<2304, 256, 0, stream>>>(W2, ww2, 589824);

  k_ln<<<8192, 64, 0, stream>>>(x, g1, be1, h1);
  k_gemm<0><<<dim3(18, 64), 256, 0, stream>>>(h1, wqkv, bqkv, nullptr, qkvb, 2304, 768);
  k_attn<<<768, 256, 0, stream>>>(qkvb, attno);
  k_gemm<1><<<dim3(6, 64), 256, 0, stream>>>(attno, wproj, bproj, x, x1, 768, 768);
  k_ln<<<8192, 64, 0, stream>>>(x1, g2, be2, h2);
  k_gemm<2><<<dim3(24, 64), 256, 0, stream>>>(h2, ww1, b1, nullptr, m1, 3072, 768);
  k_gemm<3><<<dim3(6, 64), 256, 0, stream>>>(m1, ww2, b2, x1, (float*)d_out, 768, 3072);
}

// Round 2
// 518.924 us; speedup vs baseline: 1.0655x; 1.0655x over previous
//
#include <hip/hip_runtime.h>
#include <cmath>

typedef __attribute__((ext_vector_type(4))) float f32x4;
typedef __attribute__((ext_vector_type(8))) __bf16 bf16x8;
typedef __attribute__((ext_vector_type(8))) unsigned short u16x8;
typedef __attribute__((ext_vector_type(4))) unsigned short u16x4;
typedef __attribute__((ext_vector_type(2))) unsigned int u32x2;
typedef __attribute__((ext_vector_type(4))) unsigned int u32x4;

#define DEV __device__ __forceinline__

DEV unsigned short f2b(float v) {
  __bf16 b = (__bf16)v;
  return __builtin_bit_cast(unsigned short, b);
}

// pack two f32 -> one dword of 2 bf16 (src0 -> low half)
DEV unsigned int cvtpk(float lo, float hi) {
  unsigned int r;
  asm("v_cvt_pk_bf16_f32 %0, %1, %2" : "=v"(r) : "v"(lo), "v"(hi));
  return r;
}

// hardware transpose read: per lane, 4 bf16 at elem stride 16 (32B)
DEV u32x2 tr_b16(const unsigned short* p) {
  u32x2 r;
  asm volatile("ds_read_b64_tr_b16 %0, %1"
               : "=v"(r)
               : "v"((unsigned int)(unsigned long long)p)
               : "memory");
  return r;
}

// async global->LDS, 16B per lane (wave-uniform LDS base + lane*16)
DEV void gll16(const void* g, const void* l) {
  __builtin_amdgcn_global_load_lds(
      (const __attribute__((address_space(1))) unsigned int*)(unsigned long long)g,
      (__attribute__((address_space(3))) unsigned int*)(unsigned int)(unsigned long long)l,
      16, 0, 0);
}

// ---------------- fp32 -> bf16 convert (weights) ----------------
__global__ void k_cvt_bf16(const float* __restrict__ src,
                           unsigned short* __restrict__ dst, int n4) {
  int i = blockIdx.x * blockDim.x + threadIdx.x;
  if (i >= n4) return;
  float4 v = ((const float4*)src)[i];
  u16x4 o = {f2b(v.x), f2b(v.y), f2b(v.z), f2b(v.w)};
  *(u16x4*)(dst + (size_t)i * 4) = o;
}

// ---------------- LayerNorm: fp32 [row][768] -> bf16 ----------------
__global__ void k_ln(const float* __restrict__ x, const float* __restrict__ g,
                     const float* __restrict__ be, unsigned short* __restrict__ out) {
  int row = blockIdx.x;
  int l = threadIdx.x;  // 0..63
  const float* xr = x + (size_t)row * 768;
  float4 v[3];
  float s = 0.f, sq = 0.f;
#pragma unroll
  for (int j = 0; j < 3; ++j) {
    v[j] = ((const float4*)xr)[l + 64 * j];
    s += v[j].x + v[j].y + v[j].z + v[j].w;
    sq += v[j].x * v[j].x + v[j].y * v[j].y + v[j].z * v[j].z + v[j].w * v[j].w;
  }
#pragma unroll
  for (int m = 1; m < 64; m <<= 1) {
    s += __shfl_xor(s, m);
    sq += __shfl_xor(sq, m);
  }
  float mu = s * (1.f / 768.f);
  float var = sq * (1.f / 768.f) - mu * mu;
  float rs = rsqrtf(var + 1e-6f);
  unsigned short* orow = out + (size_t)row * 768;
#pragma unroll
  for (int j = 0; j < 3; ++j) {
    int c4 = l + 64 * j;
    float4 gv = ((const float4*)g)[c4];
    float4 bv = ((const float4*)be)[c4];
    u16x4 o = {f2b((v[j].x - mu) * rs * gv.x + bv.x),
               f2b((v[j].y - mu) * rs * gv.y + bv.y),
               f2b((v[j].z - mu) * rs * gv.z + bv.z),
               f2b((v[j].w - mu) * rs * gv.w + bv.w)};
    *(u16x4*)(orow + c4 * 4) = o;
  }
}

// ---------------- GEMM: C[M,N] = A[M,K](bf16) @ B[N,K]^T(bf16) ----------------
// m97 structure + bijective XCD swizzle (all grids have nwg%8==0).
template <int MODE>
__global__ __launch_bounds__(256) void k_gemm(
    const unsigned short* __restrict__ A, const unsigned short* __restrict__ Bw,
    const float* __restrict__ bias, const float* __restrict__ res,
    void* __restrict__ outp, int N, int K) {
  __shared__ unsigned short As[128 * 32];
  __shared__ unsigned short Bs[128 * 32];
  const int tid = threadIdx.x;
  const int w = tid >> 6, l = tid & 63;
  const int wr = w >> 1, wc = w & 1;
  const int lr = l & 15, lg = l >> 4;
  // XCD-aware swizzle: contiguous chunk of blocks per XCD (nwg % 8 == 0)
  const int nwg = gridDim.x * gridDim.y;
  const int bid = blockIdx.y * gridDim.x + blockIdx.x;
  const int swz = (bid & 7) * (nwg >> 3) + (bid >> 3);
  const int bx = swz % gridDim.x, by = swz / gridDim.x;
  const int brow = by * 128, bcol = bx * 128;
  f32x4 acc[4][4] = {};
  for (int kt = 0; kt < K; kt += 32) {
    __syncthreads();
#pragma unroll
    for (int i = 0; i < 2; ++i) {
      int c = i * 256 + tid;
      gll16(A + (size_t)(brow + (c >> 2)) * K + kt + (c & 3) * 8,
            (const char*)As + (i * 256 + (w << 6)) * 16);
      gll16(Bw + (size_t)(bcol + (c >> 2)) * K + kt + (c & 3) * 8,
            (const char*)Bs + (i * 256 + (w << 6)) * 16);
    }
    asm volatile("s_waitcnt vmcnt(0)" ::: "memory");
    __syncthreads();
    bf16x8 af[4], bfr[4];
#pragma unroll
    for (int m = 0; m < 4; ++m)
      af[m] = *(const bf16x8*)&As[(wr * 64 + m * 16 + lr) * 32 + lg * 8];
#pragma unroll
    for (int n = 0; n < 4; ++n)
      bfr[n] = *(const bf16x8*)&Bs[(wc * 64 + n * 16 + lr) * 32 + lg * 8];
#pragma unroll
    for (int m = 0; m < 4; ++m)
#pragma unroll
      for (int n = 0; n < 4; ++n)
        acc[m][n] = __builtin_amdgcn_mfma_f32_16x16x32_bf16(af[m], bfr[n], acc[m][n], 0, 0, 0);
  }
#pragma unroll
  for (int n = 0; n < 4; ++n) {
    int col = bcol + wc * 64 + n * 16 + lr;
    float bv = bias[col];
#pragma unroll
    for (int m = 0; m < 4; ++m) {
      int row0 = brow + wr * 64 + m * 16 + lg * 4;
#pragma unroll
      for (int r = 0; r < 4; ++r) {
        size_t idx = (size_t)(row0 + r) * N + col;
        float v = acc[m][n][r] + bv;
        if (MODE == 0) {
          ((unsigned short*)outp)[idx] = f2b(v);
        } else if (MODE == 1) {
          ((float*)outp)[idx] = v + res[idx];
        } else if (MODE == 2) {
          ((unsigned short*)outp)[idx] = f2b(0.5f * v * (1.f + erff(v * 0.70710678f)));
        } else {
          ((float*)outp)[idx] = v + res[idx];
        }
      }
    }
  }
}

// ---------------- fused attention (flash-style, non-causal) ----------------
// 24 (b,h) x 32 q-tiles; 4 waves/block, 32 q-rows/wave, KVBLK=64.
// Swapped QK^T (S^T = K@Q^T) -> per-lane softmax (q = lane&15).
// K: padded LDS [key][72], vector-staged. V: subtiled [hd>>4][key][hd&15],
// vector ds_write_b128 staging, PV B-frags via ds_read_b64_tr_b16 (T10).
// P: in-register cvt_pk + shfl redistribution (T12-adapted), no P LDS.
__global__ __launch_bounds__(256, 3) void k_attn(const unsigned short* __restrict__ qkv,
                                                 unsigned short* __restrict__ out) {
  __shared__ unsigned short Ks[64 * 72];
  __shared__ unsigned short Vs[4 * 64 * 16];  // [hb][key][c]
  const int tid = threadIdx.x;
  const int w = tid >> 6, l = tid & 63, lr = l & 15, lg = l >> 4;
  const int bh = blockIdx.x >> 5, qt = blockIdx.x & 31;
  const int b = bh / 12, h = bh % 12;
  const size_t base = (size_t)b * 4096 * 2304;
  const int qbase = qt * 128 + w * 32;
  const float scale = 0.125f;

  // Q as B-frags of S^T = K@Q^T: lane holds q=lr, hd = ks*32 + lg*8 + j
  bf16x8 qb[2][2];
#pragma unroll
  for (int qf = 0; qf < 2; ++qf)
#pragma unroll
    for (int ks = 0; ks < 2; ++ks)
      qb[qf][ks] = *(const bf16x8*)(qkv + base + (size_t)(qbase + qf * 16 + lr) * 2304 +
                                    h * 64 + ks * 32 + lg * 8);

  f32x4 O[2][4] = {};
  float mrun[2] = {-INFINITY, -INFINITY};
  float lrun[2] = {0.f, 0.f};
  const int srcA = lr + ((lg & 1) << 5);  // lane (lr, 2*(lg&1))
  const int srcB = srcA + 16;             // lane (lr, 2*(lg&1)+1)
  const bool hsel = (lg >> 1) != 0;

  for (int kv = 0; kv < 4096; kv += 64) {
    // stage K/V tile: global->reg (issued before barrier: T14 overlap)
    u16x8 kc[2], vc[2];
#pragma unroll
    for (int i = 0; i < 2; ++i) {
      int c = i * 256 + tid;
      int key = c >> 3, hd8 = (c & 7) * 8;
      const unsigned short* src = qkv + base + (size_t)(kv + key) * 2304 + h * 64 + hd8;
      kc[i] = *(const u16x8*)(src + 768);
      vc[i] = *(const u16x8*)(src + 1536);
    }
    __syncthreads();  // all waves done reading prev tile
#pragma unroll
    for (int i = 0; i < 2; ++i) {
      int c = i * 256 + tid;
      int key = c >> 3, a = c & 7;
      *(u16x8*)&Ks[key * 72 + a * 8] = kc[i];
      // V subtiled: hb = a>>1, c0 = 8*(a&1) -> single aligned 16B write
      *(u16x8*)&Vs[(a >> 1) * 1024 + key * 16 + (a & 1) * 8] = vc[i];
    }
    __syncthreads();

    // S^T = K @ Q^T : col=q=lr, row=key=kf*16+lg*4+r
    f32x4 st[4][2] = {};
    __builtin_amdgcn_s_setprio(1);
#pragma unroll
    for (int kf = 0; kf < 4; ++kf)
#pragma unroll
      for (int ks = 0; ks < 2; ++ks) {
        bf16x8 ka = *(const bf16x8*)&Ks[(kf * 16 + lr) * 72 + ks * 32 + lg * 8];
#pragma unroll
        for (int qf = 0; qf < 2; ++qf)
          st[kf][qf] = __builtin_amdgcn_mfma_f32_16x16x32_bf16(ka, qb[qf][ks], st[kf][qf], 0, 0, 0);
      }
    __builtin_amdgcn_s_setprio(0);

    // issue V transpose-reads early; latency hides under softmax VALU
    u32x2 vt[4][2][2];  // [hf][ks][t]
#pragma unroll
    for (int hf = 0; hf < 4; ++hf)
#pragma unroll
      for (int ks = 0; ks < 2; ++ks)
#pragma unroll
        for (int t = 0; t < 2; ++t)
          vt[hf][ks][t] = tr_b16(&Vs[hf * 1024 + (ks * 32 + lg * 8 + t * 4) * 16 + lr]);

    // online softmax; lane's q = qf*16 + lr
    unsigned int pk[4][2][2];  // [kf][qf][d]
#pragma unroll
    for (int qf = 0; qf < 2; ++qf) {
      float mloc = -INFINITY;
#pragma unroll
      for (int kf = 0; kf < 4; ++kf)
#pragma unroll
        for (int r = 0; r < 4; ++r) mloc = fmaxf(mloc, st[kf][qf][r]);
      mloc = fmaxf(mloc, __shfl_xor(mloc, 16));
      mloc = fmaxf(mloc, __shfl_xor(mloc, 32));
      float mnew = fmaxf(mrun[qf], mloc);
      float alpha = __expf((mrun[qf] - mnew) * scale);
      float ssum = 0.f;
#pragma unroll
      for (int kf = 0; kf < 4; ++kf)
#pragma unroll
        for (int r = 0; r < 4; ++r) {
          float p = __expf((st[kf][qf][r] - mnew) * scale);
          st[kf][qf][r] = p;
          ssum += p;
        }
      ssum += __shfl_xor(ssum, 16);
      ssum += __shfl_xor(ssum, 32);
      lrun[qf] = lrun[qf] * alpha + ssum;
      mrun[qf] = mnew;
#pragma unroll
      for (int kf = 0; kf < 4; ++kf) {
        pk[kf][qf][0] = cvtpk(st[kf][qf][0], st[kf][qf][1]);
        pk[kf][qf][1] = cvtpk(st[kf][qf][2], st[kf][qf][3]);
      }
      // rescale O: O-frag row q' = lg*4+r; alpha for q' lives in lane q'
#pragma unroll
      for (int r = 0; r < 4; ++r) {
        float aT = __shfl(alpha, lg * 4 + r);
#pragma unroll
        for (int hf = 0; hf < 4; ++hf) O[qf][hf][r] *= aT;
      }
    }

    // redistribute P: lane (lr,lg) needs P[q=qf*16+lr][key=ks*32+lg*8+j]
    u32x4 pav[2][2];  // [qf][ks]
#pragma unroll
    for (int qf = 0; qf < 2; ++qf)
#pragma unroll
      for (int ks = 0; ks < 2; ++ks)
#pragma unroll
        for (int d = 0; d < 2; ++d) {
          unsigned int a0 = __shfl(pk[2 * ks][qf][d], srcA);
          unsigned int a1 = __shfl(pk[2 * ks + 1][qf][d], srcA);
          pav[qf][ks][d] = hsel ? a1 : a0;
          unsigned int b0 = __shfl(pk[2 * ks][qf][d], srcB);
          unsigned int b1 = __shfl(pk[2 * ks + 1][qf][d], srcB);
          pav[qf][ks][2 + d] = hsel ? b1 : b0;
        }

    // fence: tr reads + shuffles complete before MFMA consumes (rule #18)
    asm volatile("s_waitcnt lgkmcnt(0)" ::: "memory");
    __builtin_amdgcn_sched_barrier(0);

    // PV: O[q][hd] += P @ V
    __builtin_amdgcn_s_setprio(1);
#pragma unroll
    for (int ks = 0; ks < 2; ++ks)
#pragma unroll
      for (int qf = 0; qf < 2; ++qf) {
        bf16x8 paf = __builtin_bit_cast(bf16x8, pav[qf][ks]);
#pragma unroll
        for (int hf = 0; hf < 4; ++hf) {
          u32x4 vv = {vt[hf][ks][0].x, vt[hf][ks][0].y, vt[hf][ks][1].x, vt[hf][ks][1].y};
          O[qf][hf] = __builtin_amdgcn_mfma_f32_16x16x32_bf16(
              paf, __builtin_bit_cast(bf16x8, vv), O[qf][hf], 0, 0, 0);
        }
      }
    __builtin_amdgcn_s_setprio(0);
  }

  // epilogue: divide by l, write bf16 [b,t,h*64+hd]
#pragma unroll
  for (int qf = 0; qf < 2; ++qf)
#pragma unroll
    for (int r = 0; r < 4; ++r) {
      float lT = __shfl(lrun[qf], lg * 4 + r);
      float rl = 1.f / lT;
      int t = qbase + qf * 16 + lg * 4 + r;
#pragma unroll
      for (int hf = 0; hf < 4; ++hf)
        out[(size_t)(b * 4096 + t) * 768 + h * 64 + hf * 16 + lr] = f2b(O[qf][hf][r] * rl);
    }
}

// ---------------- launch ----------------
extern "C" void kernel_launch(void* const* d_in, const int* in_sizes, int n_in,
                              void* d_out, int out_size, void* d_ws, size_t ws_size,
                              hipStream_t stream) {
  const float* x = (const float*)d_in[0];
  const float* Wqkv = (const float*)d_in[1];
  const float* bqkv = (const float*)d_in[2];
  const float* Wproj = (const float*)d_in[3];
  const float* bproj = (const float*)d_in[4];
  const float* W1 = (const float*)d_in[5];
  const float* b1 = (const float*)d_in[6];
  const float* W2 = (const float*)d_in[7];
  const float* b2 = (const float*)d_in[8];
  const float* g1 = (const float*)d_in[9];
  const float* be1 = (const float*)d_in[10];
  const float* g2 = (const float*)d_in[11];
  const float* be2 = (const float*)d_in[12];

  char* ws = (char*)d_ws;
  unsigned short* wqkv = (unsigned short*)(ws + 0);
  unsigned short* wproj = (unsigned short*)(ws + 3538944);
  unsigned short* ww1 = (unsigned short*)(ws + 4718592);
  unsigned short* ww2 = (unsigned short*)(ws + 9437184);
  unsigned short* h1 = (unsigned short*)(ws + 14155776);
  unsigned short* qkvb = (unsigned short*)(ws + 26738688);
  unsigned short* attno = (unsigned short*)(ws + 64487424);
  float* x1 = (float*)(ws + 77070336);
  unsigned short* h2 = (unsigned short*)(ws + 102236160);
  unsigned short* m1 = (unsigned short*)(ws + 114819072);

  k_cvt_bf16<<<1728, 256, 0, stream>>>(Wqkv, wqkv, 442368);
  k_cvt_bf16<<<576, 256, 0, stream>>>(Wproj, wproj, 147456);
  k_cvt_bf16<<<2304, 256, 0, stream>>>(W1, ww1, 589824);
  k_cvt_bf16<<<2304, 256, 0, stream>>>(W2, ww2, 589824);

  k_ln<<<8192, 64, 0, stream>>>(x, g1, be1, h1);
  k_gemm<0><<<dim3(18, 64), 256, 0, stream>>>(h1, wqkv, bqkv, nullptr, qkvb, 2304, 768);
  k_attn<<<768, 256, 0, stream>>>(qkvb, attno);
  k_gemm<1><<<dim3(6, 64), 256, 0, stream>>>(attno, wproj, bproj, x, x1, 768, 768);
  k_ln<<<8192, 64, 0, stream>>>(x1, g2, be2, h2);
  k_gemm<2><<<dim3(24, 64), 256, 0, stream>>>(h2, ww1, b1, nullptr, m1, 3072, 768);
  k_gemm<3><<<dim3(6, 64), 256, 0, stream>>>(m1, ww2, b2, x1, (float*)d_out, 768, 3072);
}

// Round 3
// 382.024 us; speedup vs baseline: 1.4473x; 1.3584x over previous
//
#include <hip/hip_runtime.h>
#include <cmath>

typedef __attribute__((ext_vector_type(4))) float f32x4;
typedef __attribute__((ext_vector_type(16))) float f32x16;
typedef __attribute__((ext_vector_type(8))) __bf16 bf16x8;
typedef __attribute__((ext_vector_type(8))) unsigned short u16x8;
typedef __attribute__((ext_vector_type(4))) unsigned short u16x4;
typedef __attribute__((ext_vector_type(2))) unsigned int u32x2;
typedef __attribute__((ext_vector_type(4))) unsigned int u32x4;

#define DEV __device__ __forceinline__

DEV unsigned short f2b(float v) {
  __bf16 b = (__bf16)v;
  return __builtin_bit_cast(unsigned short, b);
}

// pack two f32 -> one dword of 2 bf16 (src0 -> low half)
DEV unsigned int cvtpk(float lo, float hi) {
  unsigned int r;
  asm("v_cvt_pk_bf16_f32 %0, %1, %2" : "=v"(r) : "v"(lo), "v"(hi));
  return r;
}

// raw 2^x (trans pipe)
DEV float exp2a(float x) {
  float r;
  asm("v_exp_f32 %0, %1" : "=v"(r) : "v"(x));
  return r;
}

// x.hi-lanes <-> y.lo-lanes (gfx950)
DEV void swap32(unsigned int& x, unsigned int& y) {
  asm("v_permlane32_swap_b32 %0, %1" : "+v"(x), "+v"(y));
}

// hardware transpose read: per lane, 4 bf16 at elem stride 16 (32B)
// (contract validated on HW in R1: lane gets elems E, E+16, E+32, E+48)
DEV u32x2 tr_b16(const unsigned short* p) {
  u32x2 r;
  asm volatile("ds_read_b64_tr_b16 %0, %1"
               : "=v"(r)
               : "v"((unsigned int)(unsigned long long)p)
               : "memory");
  return r;
}

// async global->LDS, 16B per lane (wave-uniform LDS base + lane*16)
DEV void gll16(const void* g, const void* l) {
  __builtin_amdgcn_global_load_lds(
      (const __attribute__((address_space(1))) unsigned int*)(unsigned long long)g,
      (__attribute__((address_space(3))) unsigned int*)(unsigned int)(unsigned long long)l,
      16, 0, 0);
}

// ---------------- fp32 -> bf16 convert (weights) ----------------
__global__ void k_cvt_bf16(const float* __restrict__ src,
                           unsigned short* __restrict__ dst, int n4) {
  int i = blockIdx.x * blockDim.x + threadIdx.x;
  if (i >= n4) return;
  float4 v = ((const float4*)src)[i];
  u16x4 o = {f2b(v.x), f2b(v.y), f2b(v.z), f2b(v.w)};
  *(u16x4*)(dst + (size_t)i * 4) = o;
}

// ---------------- LayerNorm: fp32 [row][768] -> bf16 ----------------
__global__ void k_ln(const float* __restrict__ x, const float* __restrict__ g,
                     const float* __restrict__ be, unsigned short* __restrict__ out) {
  int row = blockIdx.x;
  int l = threadIdx.x;  // 0..63
  const float* xr = x + (size_t)row * 768;
  float4 v[3];
  float s = 0.f, sq = 0.f;
#pragma unroll
  for (int j = 0; j < 3; ++j) {
    v[j] = ((const float4*)xr)[l + 64 * j];
    s += v[j].x + v[j].y + v[j].z + v[j].w;
    sq += v[j].x * v[j].x + v[j].y * v[j].y + v[j].z * v[j].z + v[j].w * v[j].w;
  }
#pragma unroll
  for (int m = 1; m < 64; m <<= 1) {
    s += __shfl_xor(s, m);
    sq += __shfl_xor(sq, m);
  }
  float mu = s * (1.f / 768.f);
  float var = sq * (1.f / 768.f) - mu * mu;
  float rs = rsqrtf(var + 1e-6f);
  unsigned short* orow = out + (size_t)row * 768;
#pragma unroll
  for (int j = 0; j < 3; ++j) {
    int c4 = l + 64 * j;
    float4 gv = ((const float4*)g)[c4];
    float4 bv = ((const float4*)be)[c4];
    u16x4 o = {f2b((v[j].x - mu) * rs * gv.x + bv.x),
               f2b((v[j].y - mu) * rs * gv.y + bv.y),
               f2b((v[j].z - mu) * rs * gv.z + bv.z),
               f2b((v[j].w - mu) * rs * gv.w + bv.w)};
    *(u16x4*)(orow + c4 * 4) = o;
  }
}

// ---------------- GEMM: C[M,N] = A[M,K](bf16) @ B[N,K]^T(bf16) ----------------
// m97 structure + bijective XCD swizzle (all grids have nwg%8==0).
template <int MODE>
__global__ __launch_bounds__(256) void k_gemm(
    const unsigned short* __restrict__ A, const unsigned short* __restrict__ Bw,
    const float* __restrict__ bias, const float* __restrict__ res,
    void* __restrict__ outp, int N, int K) {
  __shared__ unsigned short As[128 * 32];
  __shared__ unsigned short Bs[128 * 32];
  const int tid = threadIdx.x;
  const int w = tid >> 6, l = tid & 63;
  const int wr = w >> 1, wc = w & 1;
  const int lr = l & 15, lg = l >> 4;
  const int nwg = gridDim.x * gridDim.y;
  const int bid = blockIdx.y * gridDim.x + blockIdx.x;
  const int swz = (bid & 7) * (nwg >> 3) + (bid >> 3);
  const int bx = swz % gridDim.x, by = swz / gridDim.x;
  const int brow = by * 128, bcol = bx * 128;
  f32x4 acc[4][4] = {};
  for (int kt = 0; kt < K; kt += 32) {
    __syncthreads();
#pragma unroll
    for (int i = 0; i < 2; ++i) {
      int c = i * 256 + tid;
      gll16(A + (size_t)(brow + (c >> 2)) * K + kt + (c & 3) * 8,
            (const char*)As + (i * 256 + (w << 6)) * 16);
      gll16(Bw + (size_t)(bcol + (c >> 2)) * K + kt + (c & 3) * 8,
            (const char*)Bs + (i * 256 + (w << 6)) * 16);
    }
    asm volatile("s_waitcnt vmcnt(0)" ::: "memory");
    __syncthreads();
    bf16x8 af[4], bfr[4];
#pragma unroll
    for (int m = 0; m < 4; ++m)
      af[m] = *(const bf16x8*)&As[(wr * 64 + m * 16 + lr) * 32 + lg * 8];
#pragma unroll
    for (int n = 0; n < 4; ++n)
      bfr[n] = *(const bf16x8*)&Bs[(wc * 64 + n * 16 + lr) * 32 + lg * 8];
#pragma unroll
    for (int m = 0; m < 4; ++m)
#pragma unroll
      for (int n = 0; n < 4; ++n)
        acc[m][n] = __builtin_amdgcn_mfma_f32_16x16x32_bf16(af[m], bfr[n], acc[m][n], 0, 0, 0);
  }
#pragma unroll
  for (int n = 0; n < 4; ++n) {
    int col = bcol + wc * 64 + n * 16 + lr;
    float bv = bias[col];
#pragma unroll
    for (int m = 0; m < 4; ++m) {
      int row0 = brow + wr * 64 + m * 16 + lg * 4;
#pragma unroll
      for (int r = 0; r < 4; ++r) {
        size_t idx = (size_t)(row0 + r) * N + col;
        float v = acc[m][n][r] + bv;
        if (MODE == 0) {
          ((unsigned short*)outp)[idx] = f2b(v);
        } else if (MODE == 1) {
          ((float*)outp)[idx] = v + res[idx];
        } else if (MODE == 2) {
          ((unsigned short*)outp)[idx] = f2b(0.5f * v * (1.f + erff(v * 0.70710678f)));
        } else {
          ((float*)outp)[idx] = v + res[idx];
        }
      }
    }
  }
}

// ---------------- fused attention (flash, 32x32 MFMA, O^T form) ----------------
// 768 blocks (XCD-chunked), 4 waves x 32 q-rows, KVBLK=64, LDS double-buffered
// (1 barrier/iter), next-tile global prefetch issued before compute.
// S^T = K@Q^T and O^T = V^T@P^T: softmax state + rescale + 1/l all per-lane
// (col = q = lane&31). Q pre-scaled by 0.125*log2(e); exp2 domain; T13
// defer-max (THR=11). P->B-frag via 16 cvt_pk + 8 v_permlane32_swap_b32.
// K rows XOR-swizzled in LDS; V subtiled for ds_read_b64_tr_b16.
__global__ __launch_bounds__(256, 3) void k_attn(const unsigned short* __restrict__ qkv,
                                                 unsigned short* __restrict__ out) {
  __shared__ unsigned short Ks[2][64 * 64];      // [buf][key][hd^swz]
  __shared__ unsigned short Vs[2][4 * 64 * 16];  // [buf][hb][key][c]
  const int tid = threadIdx.x;
  const int w = tid >> 6, l = tid & 63;
  const int lq = l & 31, hi = l >> 5;  // col lane-id (q), k-half
  // XCD-chunked bijective swizzle: 768 = 8 * 96
  const int p = blockIdx.x;
  const int bid = (p & 7) * 96 + (p >> 3);
  const int bh = bid >> 5, qt = bid & 31;
  const int b = bh / 12, h = bh % 12;
  const size_t base = (size_t)b * 4096 * 2304;
  const int qbase = qt * 128 + w * 32;

  // Q as B-frag of S^T (col=q=lq, k: hd = s*16 + hi*8 + j), pre-scaled
  const float SC = 0.18033688f;  // 0.125 * log2(e)
  bf16x8 qb[4];
#pragma unroll
  for (int s = 0; s < 4; ++s) {
    u16x8 raw = *(const u16x8*)(qkv + base + (size_t)(qbase + lq) * 2304 + h * 64 +
                                s * 16 + hi * 8);
    u32x4 pk;
#pragma unroll
    for (int d = 0; d < 4; ++d) {
      float f0 = __builtin_bit_cast(float, (unsigned int)raw[2 * d] << 16) * SC;
      float f1 = __builtin_bit_cast(float, (unsigned int)raw[2 * d + 1] << 16) * SC;
      pk[d] = cvtpk(f0, f1);
    }
    qb[s] = __builtin_bit_cast(bf16x8, pk);
  }

  f32x16 O[2] = {};  // O^T tiles (hb): col=q=lq, row=hd
  float mrun = -1e30f, lrun = 0.f;

  // prefetch tile 0
  u16x8 kc[2], vc[2];
#pragma unroll
  for (int i = 0; i < 2; ++i) {
    int c = i * 256 + tid;
    const unsigned short* src = qkv + base + (size_t)(c >> 3) * 2304 + h * 64 + (c & 7) * 8;
    kc[i] = *(const u16x8*)(src + 768);
    vc[i] = *(const u16x8*)(src + 1536);
  }

  int it = 0;
  for (int kv = 0; kv < 4096; kv += 64, it ^= 1) {
    // write prefetched tile -> buf[it]
#pragma unroll
    for (int i = 0; i < 2; ++i) {
      int c = i * 256 + tid;
      int key = c >> 3, a = c & 7;
      *(u16x8*)&Ks[it][key * 64 + ((a * 8) ^ ((key & 7) << 3))] = kc[i];
      *(u16x8*)&Vs[it][(a >> 1) * 1024 + key * 16 + (a & 1) * 8] = vc[i];
    }
    __syncthreads();  // single barrier/iter (dbuf makes it sufficient)

    // issue next tile's global loads; latency hides under compute
    {
      int kvn = (kv + 64) & 4095;
#pragma unroll
      for (int i = 0; i < 2; ++i) {
        int c = i * 256 + tid;
        const unsigned short* src =
            qkv + base + (size_t)(kvn + (c >> 3)) * 2304 + h * 64 + (c & 7) * 8;
        kc[i] = *(const u16x8*)(src + 768);
        vc[i] = *(const u16x8*)(src + 1536);
      }
    }

    // S^T = K @ Q^T : two 32x32 tiles (kt), 4 k-steps each
    f32x16 st[2] = {{0}, {0}};
    __builtin_amdgcn_s_setprio(1);
#pragma unroll
    for (int kt = 0; kt < 2; ++kt) {
      int key = kt * 32 + lq;
#pragma unroll
      for (int s = 0; s < 4; ++s) {
        bf16x8 ka =
            *(const bf16x8*)&Ks[it][key * 64 + ((s * 16 + hi * 8) ^ ((key & 7) << 3))];
        st[kt] = __builtin_amdgcn_mfma_f32_32x32x16_bf16(ka, qb[s], st[kt], 0, 0, 0);
      }
    }
    __builtin_amdgcn_s_setprio(0);

    // ---- softmax (per-lane, q = lq; rows = keys in regs) ----
    float pmax = st[0][0];
#pragma unroll
    for (int kt = 0; kt < 2; ++kt)
#pragma unroll
      for (int r = (kt == 0 ? 1 : 0); r < 16; ++r) pmax = fmaxf(pmax, st[kt][r]);
    pmax = fmaxf(pmax, __shfl_xor(pmax, 32));
    if (!__all(pmax - mrun <= 11.0f)) {  // T13 defer-max (2^11 headroom)
      float mnew = fmaxf(mrun, pmax);
      float al = exp2a(mrun - mnew);
      lrun *= al;
#pragma unroll
      for (int hb = 0; hb < 2; ++hb)
#pragma unroll
        for (int r = 0; r < 16; ++r) O[hb][r] *= al;
      mrun = mnew;
    }
    float s0 = 0.f;
#pragma unroll
    for (int kt = 0; kt < 2; ++kt)
#pragma unroll
      for (int r = 0; r < 16; ++r) {
        float pv = exp2a(st[kt][r] - mrun);
        st[kt][r] = pv;
        s0 += pv;
      }
    lrun += s0 + __shfl_xor(s0, 32);

    // ---- P -> B-frags of P^T (col=q): cvt_pk + permlane32_swap ----
    u32x4 pf[4];  // [kstep] = {j01,j23,j45,j67}
#pragma unroll
    for (int kt = 0; kt < 2; ++kt)
#pragma unroll
      for (int h2 = 0; h2 < 2; ++h2) {
        int r0 = h2 * 8;
        unsigned int a0 = cvtpk(st[kt][r0 + 0], st[kt][r0 + 1]);
        unsigned int a1 = cvtpk(st[kt][r0 + 2], st[kt][r0 + 3]);
        unsigned int b0 = cvtpk(st[kt][r0 + 4], st[kt][r0 + 5]);
        unsigned int b1 = cvtpk(st[kt][r0 + 6], st[kt][r0 + 7]);
        swap32(a0, b0);
        swap32(a1, b1);
        pf[kt * 2 + h2] = u32x4{a0, a1, b0, b1};
      }

    // ---- PV: O^T += V^T @ P^T, per-hb tr-read V then 4 MFMA ----
#pragma unroll
    for (int hb = 0; hb < 2; ++hb) {
      u32x2 vt[4][2];
      const unsigned short* vbase = &Vs[it][(hb * 2 + (lq >> 4)) * 1024 + (lq & 15)];
#pragma unroll
      for (int s = 0; s < 4; ++s)
#pragma unroll
        for (int t = 0; t < 2; ++t)
          vt[s][t] = tr_b16(vbase + ((s * 16 + hi * 8 + t * 4) << 4));
      asm volatile("s_waitcnt lgkmcnt(0)" ::: "memory");
      __builtin_amdgcn_sched_barrier(0);
      __builtin_amdgcn_s_setprio(1);
#pragma unroll
      for (int s = 0; s < 4; ++s) {
        u32x4 vv = {vt[s][0].x, vt[s][0].y, vt[s][1].x, vt[s][1].y};
        O[hb] = __builtin_amdgcn_mfma_f32_32x32x16_bf16(
            __builtin_bit_cast(bf16x8, vv), __builtin_bit_cast(bf16x8, pf[s]), O[hb], 0, 0, 0);
      }
      __builtin_amdgcn_s_setprio(0);
    }
  }

  // ---- epilogue: per-lane 1/l, pack pairs, 8B stores ----
  float rl = 1.f / lrun;
  unsigned short* orow = out + (size_t)(b * 4096 + qbase + lq) * 768 + h * 64;
#pragma unroll
  for (int hb = 0; hb < 2; ++hb)
#pragma unroll
    for (int g = 0; g < 4; ++g) {
      unsigned int d0 = cvtpk(O[hb][4 * g + 0] * rl, O[hb][4 * g + 1] * rl);
      unsigned int d1 = cvtpk(O[hb][4 * g + 2] * rl, O[hb][4 * g + 3] * rl);
      *(u32x2*)(orow + hb * 32 + 8 * g + 4 * hi) = u32x2{d0, d1};
    }
}

// ---------------- launch ----------------
extern "C" void kernel_launch(void* const* d_in, const int* in_sizes, int n_in,
                              void* d_out, int out_size, void* d_ws, size_t ws_size,
                              hipStream_t stream) {
  const float* x = (const float*)d_in[0];
  const float* Wqkv = (const float*)d_in[1];
  const float* bqkv = (const float*)d_in[2];
  const float* Wproj = (const float*)d_in[3];
  const float* bproj = (const float*)d_in[4];
  const float* W1 = (const float*)d_in[5];
  const float* b1 = (const float*)d_in[6];
  const float* W2 = (const float*)d_in[7];
  const float* b2 = (const float*)d_in[8];
  const float* g1 = (const float*)d_in[9];
  const float* be1 = (const float*)d_in[10];
  const float* g2 = (const float*)d_in[11];
  const float* be2 = (const float*)d_in[12];

  char* ws = (char*)d_ws;
  unsigned short* wqkv = (unsigned short*)(ws + 0);
  unsigned short* wproj = (unsigned short*)(ws + 3538944);
  unsigned short* ww1 = (unsigned short*)(ws + 4718592);
  unsigned short* ww2 = (unsigned short*)(ws + 9437184);
  unsigned short* h1 = (unsigned short*)(ws + 14155776);
  unsigned short* qkvb = (unsigned short*)(ws + 26738688);
  unsigned short* attno = (unsigned short*)(ws + 64487424);
  float* x1 = (float*)(ws + 77070336);
  unsigned short* h2 = (unsigned short*)(ws + 102236160);
  unsigned short* m1 = (unsigned short*)(ws + 114819072);

  k_cvt_bf16<<<1728, 256, 0, stream>>>(Wqkv, wqkv, 442368);
  k_cvt_bf16<<<576, 256, 0, stream>>>(Wproj, wproj, 147456);
  k_cvt_bf16<<<2304, 256, 0, stream>>>(W1, ww1, 589824);
  k_cvt_bf16<<<2304, 256, 0, stream>>>(W2, ww2, 589824);

  k_ln<<<8192, 64, 0, stream>>>(x, g1, be1, h1);
  k_gemm<0><<<dim3(18, 64), 256, 0, stream>>>(h1, wqkv, bqkv, nullptr, qkvb, 2304, 768);
  k_attn<<<768, 256, 0, stream>>>(qkvb, attno);
  k_gemm<1><<<dim3(6, 64), 256, 0, stream>>>(attno, wproj, bproj, x, x1, 768, 768);
  k_ln<<<8192, 64, 0, stream>>>(x1, g2, be2, h2);
  k_gemm<2><<<dim3(24, 64), 256, 0, stream>>>(h2, ww1, b1, nullptr, m1, 3072, 768);
  k_gemm<3><<<dim3(6, 64), 256, 0, stream>>>(m1, ww2, b2, x1, (float*)d_out, 768, 3072);
}

// Round 4
// 374.379 us; speedup vs baseline: 1.4769x; 1.0204x over previous
//
#include <hip/hip_runtime.h>
#include <cmath>

typedef __attribute__((ext_vector_type(4))) float f32x4;
typedef __attribute__((ext_vector_type(16))) float f32x16;
typedef __attribute__((ext_vector_type(8))) __bf16 bf16x8;
typedef __attribute__((ext_vector_type(8))) unsigned short u16x8;
typedef __attribute__((ext_vector_type(4))) unsigned short u16x4;
typedef __attribute__((ext_vector_type(2))) unsigned int u32x2;
typedef __attribute__((ext_vector_type(4))) unsigned int u32x4;

#define DEV __device__ __forceinline__

DEV unsigned short f2b(float v) {
  __bf16 b = (__bf16)v;
  return __builtin_bit_cast(unsigned short, b);
}

// pack two f32 -> one dword of 2 bf16 (src0 -> low half)
DEV unsigned int cvtpk(float lo, float hi) {
  unsigned int r;
  asm("v_cvt_pk_bf16_f32 %0, %1, %2" : "=v"(r) : "v"(lo), "v"(hi));
  return r;
}

// raw 2^x (trans pipe)
DEV float exp2a(float x) {
  float r;
  asm("v_exp_f32 %0, %1" : "=v"(r) : "v"(x));
  return r;
}

// x.hi-lanes <-> y.lo-lanes (gfx950)
DEV void swap32(unsigned int& x, unsigned int& y) {
  asm("v_permlane32_swap_b32 %0, %1" : "+v"(x), "+v"(y));
}

// hardware transpose read: per lane, 4 bf16 at elem stride 16 (32B)
DEV u32x2 tr_b16(const unsigned short* p) {
  u32x2 r;
  asm volatile("ds_read_b64_tr_b16 %0, %1"
               : "=v"(r)
               : "v"((unsigned int)(unsigned long long)p)
               : "memory");
  return r;
}

// async global->LDS, 16B per lane (wave-uniform LDS base; HW: lane l -> base+16l)
DEV void gll16(const void* g, const void* l) {
  __builtin_amdgcn_global_load_lds(
      (const __attribute__((address_space(1))) unsigned int*)(unsigned long long)g,
      (__attribute__((address_space(3))) unsigned int*)(unsigned int)(unsigned long long)l,
      16, 0, 0);
}

// ---------------- fp32 -> bf16 convert (weights) ----------------
__global__ void k_cvt_bf16(const float* __restrict__ src,
                           unsigned short* __restrict__ dst, int n4) {
  int i = blockIdx.x * blockDim.x + threadIdx.x;
  if (i >= n4) return;
  float4 v = ((const float4*)src)[i];
  u16x4 o = {f2b(v.x), f2b(v.y), f2b(v.z), f2b(v.w)};
  *(u16x4*)(dst + (size_t)i * 4) = o;
}

// ---------------- LayerNorm: fp32 [row][768] -> bf16 ----------------
__global__ void k_ln(const float* __restrict__ x, const float* __restrict__ g,
                     const float* __restrict__ be, unsigned short* __restrict__ out) {
  int row = blockIdx.x;
  int l = threadIdx.x;  // 0..63
  const float* xr = x + (size_t)row * 768;
  float4 v[3];
  float s = 0.f, sq = 0.f;
#pragma unroll
  for (int j = 0; j < 3; ++j) {
    v[j] = ((const float4*)xr)[l + 64 * j];
    s += v[j].x + v[j].y + v[j].z + v[j].w;
    sq += v[j].x * v[j].x + v[j].y * v[j].y + v[j].z * v[j].z + v[j].w * v[j].w;
  }
#pragma unroll
  for (int m = 1; m < 64; m <<= 1) {
    s += __shfl_xor(s, m);
    sq += __shfl_xor(sq, m);
  }
  float mu = s * (1.f / 768.f);
  float var = sq * (1.f / 768.f) - mu * mu;
  float rs = rsqrtf(var + 1e-6f);
  unsigned short* orow = out + (size_t)row * 768;
#pragma unroll
  for (int j = 0; j < 3; ++j) {
    int c4 = l + 64 * j;
    float4 gv = ((const float4*)g)[c4];
    float4 bv = ((const float4*)be)[c4];
    u16x4 o = {f2b((v[j].x - mu) * rs * gv.x + bv.x),
               f2b((v[j].y - mu) * rs * gv.y + bv.y),
               f2b((v[j].z - mu) * rs * gv.z + bv.z),
               f2b((v[j].w - mu) * rs * gv.w + bv.w)};
    *(u16x4*)(orow + c4 * 4) = o;
  }
}

// ---------------- GEMM: C[M,N] = A[M,K](bf16) @ B[N,K]^T(bf16) ----------------
// m97 structure, BM templated (64 for skinny-N GEMMs -> balanced 3 blocks/CU),
// bijective XCD swizzle (all grids have nwg%8==0).
template <int MODE, int BM>
__global__ __launch_bounds__(256) void k_gemm(
    const unsigned short* __restrict__ A, const unsigned short* __restrict__ Bw,
    const float* __restrict__ bias, const float* __restrict__ res,
    void* __restrict__ outp, int N, int K) {
  __shared__ unsigned short As[BM * 32];
  __shared__ unsigned short Bs[128 * 32];
  constexpr int MR = BM / 32;  // m-frags per wave
  constexpr int AI = BM / 64;  // A staging issues
  const int tid = threadIdx.x;
  const int w = tid >> 6, l = tid & 63;
  const int wr = w >> 1, wc = w & 1;
  const int lr = l & 15, lg = l >> 4;
  const int nwg = gridDim.x * gridDim.y;
  const int bid = blockIdx.y * gridDim.x + blockIdx.x;
  const int swz = (bid & 7) * (nwg >> 3) + (bid >> 3);
  const int bx = swz % gridDim.x, by = swz / gridDim.x;
  const int brow = by * BM, bcol = bx * 128;
  f32x4 acc[MR][4] = {};
  for (int kt = 0; kt < K; kt += 32) {
    __syncthreads();
#pragma unroll
    for (int i = 0; i < AI; ++i) {
      int c = i * 256 + tid;
      gll16(A + (size_t)(brow + (c >> 2)) * K + kt + (c & 3) * 8,
            (const char*)As + (i * 256 + (w << 6)) * 16);
    }
#pragma unroll
    for (int i = 0; i < 2; ++i) {
      int c = i * 256 + tid;
      gll16(Bw + (size_t)(bcol + (c >> 2)) * K + kt + (c & 3) * 8,
            (const char*)Bs + (i * 256 + (w << 6)) * 16);
    }
    asm volatile("s_waitcnt vmcnt(0)" ::: "memory");
    __syncthreads();
    bf16x8 af[MR], bfr[4];
#pragma unroll
    for (int m = 0; m < MR; ++m)
      af[m] = *(const bf16x8*)&As[(wr * (BM / 2) + m * 16 + lr) * 32 + lg * 8];
#pragma unroll
    for (int n = 0; n < 4; ++n)
      bfr[n] = *(const bf16x8*)&Bs[(wc * 64 + n * 16 + lr) * 32 + lg * 8];
#pragma unroll
    for (int m = 0; m < MR; ++m)
#pragma unroll
      for (int n = 0; n < 4; ++n)
        acc[m][n] = __builtin_amdgcn_mfma_f32_16x16x32_bf16(af[m], bfr[n], acc[m][n], 0, 0, 0);
  }
#pragma unroll
  for (int n = 0; n < 4; ++n) {
    int col = bcol + wc * 64 + n * 16 + lr;
    float bv = bias[col];
#pragma unroll
    for (int m = 0; m < MR; ++m) {
      int row0 = brow + wr * (BM / 2) + m * 16 + lg * 4;
#pragma unroll
      for (int r = 0; r < 4; ++r) {
        size_t idx = (size_t)(row0 + r) * N + col;
        float v = acc[m][n][r] + bv;
        if (MODE == 0) {
          ((unsigned short*)outp)[idx] = f2b(v);
        } else if (MODE == 1) {
          ((float*)outp)[idx] = v + res[idx];
        } else if (MODE == 2) {
          ((unsigned short*)outp)[idx] = f2b(0.5f * v * (1.f + erff(v * 0.70710678f)));
        } else {
          ((float*)outp)[idx] = v + res[idx];
        }
      }
    }
  }
}

// ---------------- fused attention (flash, 32x32 MFMA, O^T form) ----------------
// R3 structure (S^T=K@Q^T, O^T=V^T@P^T, per-lane softmax, exp2 domain,
// defer-max, cvt_pk+permlane32_swap, tr_b16 PV) with staging moved to
// global_load_lds: K's XOR swizzle is applied to the GLOBAL source column
// (m173 pre-swizzle), LDS dest stays linear; V's subtiled layout is linear
// per 1KB chunk. Prefetch issued right after the barrier -> full compute
// phase between issue and next iter's vmcnt(0).
__global__ __launch_bounds__(256, 3) void k_attn(const unsigned short* __restrict__ qkv,
                                                 unsigned short* __restrict__ out) {
  __shared__ unsigned short Ks[2][64 * 64];      // [buf][key][hd-grp ^ (key&7)]
  __shared__ unsigned short Vs[2][4 * 64 * 16];  // [buf][hb][key][c]
  const int tid = threadIdx.x;
  const int w = tid >> 6, l = tid & 63;
  const int lq = l & 31, hi = l >> 5;
  // XCD-chunked bijective swizzle: 768 = 8 * 96
  const int p = blockIdx.x;
  const int bid = (p & 7) * 96 + (p >> 3);
  const int bh = bid >> 5, qt = bid & 31;
  const int b = bh / 12, h = bh % 12;
  const size_t base = (size_t)b * 4096 * 2304;
  const int qbase = qt * 128 + w * 32;

  // Q as B-frag of S^T (col=q=lq, k: hd = s*16 + hi*8 + j), pre-scaled
  const float SC = 0.18033688f;  // 0.125 * log2(e)
  bf16x8 qb[4];
#pragma unroll
  for (int s = 0; s < 4; ++s) {
    u16x8 raw = *(const u16x8*)(qkv + base + (size_t)(qbase + lq) * 2304 + h * 64 +
                                s * 16 + hi * 8);
    u32x4 pk;
#pragma unroll
    for (int d = 0; d < 4; ++d) {
      float f0 = __builtin_bit_cast(float, (unsigned int)raw[2 * d] << 16) * SC;
      float f1 = __builtin_bit_cast(float, (unsigned int)raw[2 * d + 1] << 16) * SC;
      pk[d] = cvtpk(f0, f1);
    }
    qb[s] = __builtin_bit_cast(bf16x8, pk);
  }

  // per-lane gll16 sources. K: wave w stages key rows [16w,16w+16) with the
  // XOR swizzle folded into the source column group; V: subtile hb=w, linear.
  const unsigned short* pK = qkv + base + (size_t)(16 * w + (l >> 3)) * 2304 + 768 +
                             h * 64 + (((l & 7) ^ ((l >> 3) & 7)) << 3);
  const unsigned short* pV =
      qkv + base + (size_t)(l >> 1) * 2304 + 1536 + h * 64 + w * 16 + ((l & 1) << 3);
  const size_t STEP = (size_t)64 * 2304;

  // prologue: tile 0 -> buf 0 (4 gll16 per thread)
  {
    const char* dK = (const char*)&Ks[0][0] + w * 2048;
    const char* dV = (const char*)&Vs[0][0] + w * 2048;
    gll16(pK, dK);
    gll16(pK + 8 * 2304, dK + 1024);
    gll16(pV, dV);
    gll16(pV + 32 * 2304, dV + 1024);
    pK += STEP;
    pV += STEP;
  }

  f32x16 O[2] = {};  // O^T tiles (hb): col=q=lq, row=hd
  float mrun = -1e30f, lrun = 0.f;

  int it = 0;
  for (int t = 0; t < 64; ++t, it ^= 1) {
    asm volatile("s_waitcnt vmcnt(0)" ::: "memory");  // this wave's tile landed
    __syncthreads();                                  // all waves' tiles landed
    if (t < 63) {  // issue next tile into the other buffer; lands during compute
      const char* dK = (const char*)&Ks[it ^ 1][0] + w * 2048;
      const char* dV = (const char*)&Vs[it ^ 1][0] + w * 2048;
      gll16(pK, dK);
      gll16(pK + 8 * 2304, dK + 1024);
      gll16(pV, dV);
      gll16(pV + 32 * 2304, dV + 1024);
      pK += STEP;
      pV += STEP;
    }

    // S^T = K @ Q^T : two 32x32 tiles (kt), 4 k-steps each
    f32x16 st[2] = {{0}, {0}};
    __builtin_amdgcn_s_setprio(1);
#pragma unroll
    for (int kt = 0; kt < 2; ++kt) {
      int key = kt * 32 + lq;
#pragma unroll
      for (int s = 0; s < 4; ++s) {
        bf16x8 ka =
            *(const bf16x8*)&Ks[it][key * 64 + ((s * 16 + hi * 8) ^ ((key & 7) << 3))];
        st[kt] = __builtin_amdgcn_mfma_f32_32x32x16_bf16(ka, qb[s], st[kt], 0, 0, 0);
      }
    }
    __builtin_amdgcn_s_setprio(0);

    // ---- softmax (per-lane, q = lq; rows = keys in regs) ----
    float pmax = st[0][0];
#pragma unroll
    for (int kt = 0; kt < 2; ++kt)
#pragma unroll
      for (int r = (kt == 0 ? 1 : 0); r < 16; ++r) pmax = fmaxf(pmax, st[kt][r]);
    pmax = fmaxf(pmax, __shfl_xor(pmax, 32));
    if (!__all(pmax - mrun <= 11.0f)) {  // T13 defer-max (2^11 headroom)
      float mnew = fmaxf(mrun, pmax);
      float al = exp2a(mrun - mnew);
      lrun *= al;
#pragma unroll
      for (int hb = 0; hb < 2; ++hb)
#pragma unroll
        for (int r = 0; r < 16; ++r) O[hb][r] *= al;
      mrun = mnew;
    }
    float s0 = 0.f;
#pragma unroll
    for (int kt = 0; kt < 2; ++kt)
#pragma unroll
      for (int r = 0; r < 16; ++r) {
        float pv = exp2a(st[kt][r] - mrun);
        st[kt][r] = pv;
        s0 += pv;
      }
    lrun += s0 + __shfl_xor(s0, 32);

    // ---- P -> B-frags of P^T (col=q): cvt_pk + permlane32_swap ----
    u32x4 pf[4];  // [kstep] = {j01,j23,j45,j67}
#pragma unroll
    for (int kt = 0; kt < 2; ++kt)
#pragma unroll
      for (int h2 = 0; h2 < 2; ++h2) {
        int r0 = h2 * 8;
        unsigned int a0 = cvtpk(st[kt][r0 + 0], st[kt][r0 + 1]);
        unsigned int a1 = cvtpk(st[kt][r0 + 2], st[kt][r0 + 3]);
        unsigned int b0 = cvtpk(st[kt][r0 + 4], st[kt][r0 + 5]);
        unsigned int b1 = cvtpk(st[kt][r0 + 6], st[kt][r0 + 7]);
        swap32(a0, b0);
        swap32(a1, b1);
        pf[kt * 2 + h2] = u32x4{a0, a1, b0, b1};
      }

    // ---- PV: O^T += V^T @ P^T, per-hb tr-read V then 4 MFMA ----
#pragma unroll
    for (int hb = 0; hb < 2; ++hb) {
      u32x2 vt[4][2];
      const unsigned short* vbase = &Vs[it][(hb * 2 + (lq >> 4)) * 1024 + (lq & 15)];
#pragma unroll
      for (int s = 0; s < 4; ++s)
#pragma unroll
        for (int t2 = 0; t2 < 2; ++t2)
          vt[s][t2] = tr_b16(vbase + ((s * 16 + hi * 8 + t2 * 4) << 4));
      asm volatile("s_waitcnt lgkmcnt(0)" ::: "memory");
      __builtin_amdgcn_sched_barrier(0);
      __builtin_amdgcn_s_setprio(1);
#pragma unroll
      for (int s = 0; s < 4; ++s) {
        u32x4 vv = {vt[s][0].x, vt[s][0].y, vt[s][1].x, vt[s][1].y};
        O[hb] = __builtin_amdgcn_mfma_f32_32x32x16_bf16(
            __builtin_bit_cast(bf16x8, vv), __builtin_bit_cast(bf16x8, pf[s]), O[hb], 0, 0, 0);
      }
      __builtin_amdgcn_s_setprio(0);
    }
  }

  // ---- epilogue: per-lane 1/l, pack pairs, 8B stores ----
  float rl = 1.f / lrun;
  unsigned short* orow = out + (size_t)(b * 4096 + qbase + lq) * 768 + h * 64;
#pragma unroll
  for (int hb = 0; hb < 2; ++hb)
#pragma unroll
    for (int g = 0; g < 4; ++g) {
      unsigned int d0 = cvtpk(O[hb][4 * g + 0] * rl, O[hb][4 * g + 1] * rl);
      unsigned int d1 = cvtpk(O[hb][4 * g + 2] * rl, O[hb][4 * g + 3] * rl);
      *(u32x2*)(orow + hb * 32 + 8 * g + 4 * hi) = u32x2{d0, d1};
    }
}

// ---------------- launch ----------------
extern "C" void kernel_launch(void* const* d_in, const int* in_sizes, int n_in,
                              void* d_out, int out_size, void* d_ws, size_t ws_size,
                              hipStream_t stream) {
  const float* x = (const float*)d_in[0];
  const float* Wqkv = (const float*)d_in[1];
  const float* bqkv = (const float*)d_in[2];
  const float* Wproj = (const float*)d_in[3];
  const float* bproj = (const float*)d_in[4];
  const float* W1 = (const float*)d_in[5];
  const float* b1 = (const float*)d_in[6];
  const float* W2 = (const float*)d_in[7];
  const float* b2 = (const float*)d_in[8];
  const float* g1 = (const float*)d_in[9];
  const float* be1 = (const float*)d_in[10];
  const float* g2 = (const float*)d_in[11];
  const float* be2 = (const float*)d_in[12];

  char* ws = (char*)d_ws;
  unsigned short* wqkv = (unsigned short*)(ws + 0);
  unsigned short* wproj = (unsigned short*)(ws + 3538944);
  unsigned short* ww1 = (unsigned short*)(ws + 4718592);
  unsigned short* ww2 = (unsigned short*)(ws + 9437184);
  unsigned short* h1 = (unsigned short*)(ws + 14155776);
  unsigned short* qkvb = (unsigned short*)(ws + 26738688);
  unsigned short* attno = (unsigned short*)(ws + 64487424);
  float* x1 = (float*)(ws + 77070336);
  unsigned short* h2 = (unsigned short*)(ws + 102236160);
  unsigned short* m1 = (unsigned short*)(ws + 114819072);

  k_cvt_bf16<<<1728, 256, 0, stream>>>(Wqkv, wqkv, 442368);
  k_cvt_bf16<<<576, 256, 0, stream>>>(Wproj, wproj, 147456);
  k_cvt_bf16<<<2304, 256, 0, stream>>>(W1, ww1, 589824);
  k_cvt_bf16<<<2304, 256, 0, stream>>>(W2, ww2, 589824);

  k_ln<<<8192, 64, 0, stream>>>(x, g1, be1, h1);
  k_gemm<0, 128><<<dim3(18, 64), 256, 0, stream>>>(h1, wqkv, bqkv, nullptr, qkvb, 2304, 768);
  k_attn<<<768, 256, 0, stream>>>(qkvb, attno);
  k_gemm<1, 64><<<dim3(6, 128), 256, 0, stream>>>(attno, wproj, bproj, x, x1, 768, 768);
  k_ln<<<8192, 64, 0, stream>>>(x1, g2, be2, h2);
  k_gemm<2, 128><<<dim3(24, 64), 256, 0, stream>>>(h2, ww1, b1, nullptr, m1, 3072, 768);
  k_gemm<3, 64><<<dim3(6, 128), 256, 0, stream>>>(m1, ww2, b2, x1, (float*)d_out, 768, 3072);
}

// Round 5
// 365.645 us; speedup vs baseline: 1.5121x; 1.0239x over previous
//
#include <hip/hip_runtime.h>
#include <cmath>

typedef __attribute__((ext_vector_type(4))) float f32x4;
typedef __attribute__((ext_vector_type(16))) float f32x16;
typedef __attribute__((ext_vector_type(8))) __bf16 bf16x8;
typedef __attribute__((ext_vector_type(8))) unsigned short u16x8;
typedef __attribute__((ext_vector_type(4))) unsigned short u16x4;
typedef __attribute__((ext_vector_type(2))) unsigned int u32x2;
typedef __attribute__((ext_vector_type(4))) unsigned int u32x4;

#define DEV __device__ __forceinline__

DEV unsigned short f2b(float v) {
  __bf16 b = (__bf16)v;
  return __builtin_bit_cast(unsigned short, b);
}

DEV unsigned int cvtpk(float lo, float hi) {
  unsigned int r;
  asm("v_cvt_pk_bf16_f32 %0, %1, %2" : "=v"(r) : "v"(lo), "v"(hi));
  return r;
}

DEV float exp2a(float x) {
  float r;
  asm("v_exp_f32 %0, %1" : "=v"(r) : "v"(x));
  return r;
}

DEV void swap32(unsigned int& x, unsigned int& y) {
  asm("v_permlane32_swap_b32 %0, %1" : "+v"(x), "+v"(y));
}

DEV u32x2 tr_b16(const unsigned short* p) {
  u32x2 r;
  asm volatile("ds_read_b64_tr_b16 %0, %1"
               : "=v"(r)
               : "v"((unsigned int)(unsigned long long)p)
               : "memory");
  return r;
}

DEV void gll16(const void* g, const void* l) {
  __builtin_amdgcn_global_load_lds(
      (const __attribute__((address_space(1))) unsigned int*)(unsigned long long)g,
      (__attribute__((address_space(3))) unsigned int*)(unsigned int)(unsigned long long)l,
      16, 0, 0);
}

// ---------------- fp32 -> bf16 convert (weights) ----------------
__global__ void k_cvt_bf16(const float* __restrict__ src,
                           unsigned short* __restrict__ dst, int n4) {
  int i = blockIdx.x * blockDim.x + threadIdx.x;
  if (i >= n4) return;
  float4 v = ((const float4*)src)[i];
  u16x4 o = {f2b(v.x), f2b(v.y), f2b(v.z), f2b(v.w)};
  *(u16x4*)(dst + (size_t)i * 4) = o;
}

// ---------------- LayerNorm: fp32 [row][768] -> bf16 ----------------
__global__ void k_ln(const float* __restrict__ x, const float* __restrict__ g,
                     const float* __restrict__ be, unsigned short* __restrict__ out) {
  int row = blockIdx.x;
  int l = threadIdx.x;  // 0..63
  const float* xr = x + (size_t)row * 768;
  float4 v[3];
  float s = 0.f, sq = 0.f;
#pragma unroll
  for (int j = 0; j < 3; ++j) {
    v[j] = ((const float4*)xr)[l + 64 * j];
    s += v[j].x + v[j].y + v[j].z + v[j].w;
    sq += v[j].x * v[j].x + v[j].y * v[j].y + v[j].z * v[j].z + v[j].w * v[j].w;
  }
#pragma unroll
  for (int m = 1; m < 64; m <<= 1) {
    s += __shfl_xor(s, m);
    sq += __shfl_xor(sq, m);
  }
  float mu = s * (1.f / 768.f);
  float var = sq * (1.f / 768.f) - mu * mu;
  float rs = rsqrtf(var + 1e-6f);
  unsigned short* orow = out + (size_t)row * 768;
#pragma unroll
  for (int j = 0; j < 3; ++j) {
    int c4 = l + 64 * j;
    float4 gv = ((const float4*)g)[c4];
    float4 bv = ((const float4*)be)[c4];
    u16x4 o = {f2b((v[j].x - mu) * rs * gv.x + bv.x),
               f2b((v[j].y - mu) * rs * gv.y + bv.y),
               f2b((v[j].z - mu) * rs * gv.z + bv.z),
               f2b((v[j].w - mu) * rs * gv.w + bv.w)};
    *(u16x4*)(orow + c4 * 4) = o;
  }
}

// ---------------- GEMM: C[M,N] = A[M,K](bf16) @ B[N,K]^T(bf16) ----------------
// m97-style staging, BK=64 (half the barrier/vmcnt drains per FLOP), XOR
// swizzle on BOTH gll16 source and ds_read (rule #21 involution) -> A/B
// fragment reads conflict-free. BM templated; bijective XCD swizzle.
template <int MODE, int BM>
__global__ __launch_bounds__(256) void k_gemm(
    const unsigned short* __restrict__ A, const unsigned short* __restrict__ Bw,
    const float* __restrict__ bias, const float* __restrict__ res,
    void* __restrict__ outp, int N, int K) {
  __shared__ unsigned short As[BM * 64];
  __shared__ unsigned short Bs[128 * 64];
  constexpr int MR = BM / 32;  // m-frags per wave
  constexpr int AI = BM / 32;  // A staging issues (BM rows * 128B / 4KB)
  const int tid = threadIdx.x;
  const int w = tid >> 6, l = tid & 63;
  const int wr = w >> 1, wc = w & 1;
  const int lr = l & 15, lg = l >> 4;
  const int nwg = gridDim.x * gridDim.y;
  const int bid = blockIdx.y * gridDim.x + blockIdx.x;
  const int swz = (bid & 7) * (nwg >> 3) + (bid >> 3);
  const int bx = swz % gridDim.x, by = swz / gridDim.x;
  const int brow = by * BM, bcol = bx * 128;
  // staging decomposition: c = i*256+tid -> row = c>>3, col-group = c&7.
  // LDS dest linear; global source col-group pre-swizzled: (c&7)^(row&7).
  f32x4 acc[MR][4] = {};
  for (int kt = 0; kt < K; kt += 64) {
    __syncthreads();
#pragma unroll
    for (int i = 0; i < AI; ++i) {
      int c = i * 256 + tid;
      int row = c >> 3, cg = (c & 7) ^ (row & 7);
      gll16(A + (size_t)(brow + row) * K + kt + cg * 8,
            (const char*)As + (i * 256 + (w << 6)) * 16);
    }
#pragma unroll
    for (int i = 0; i < 4; ++i) {
      int c = i * 256 + tid;
      int row = c >> 3, cg = (c & 7) ^ (row & 7);
      gll16(Bw + (size_t)(bcol + row) * K + kt + cg * 8,
            (const char*)Bs + (i * 256 + (w << 6)) * 16);
    }
    asm volatile("s_waitcnt vmcnt(0)" ::: "memory");
    __syncthreads();
    bf16x8 af[MR][2], bfr[4][2];
#pragma unroll
    for (int m = 0; m < MR; ++m) {
      int row = wr * (BM / 2) + m * 16 + lr;
#pragma unroll
      for (int s = 0; s < 2; ++s)
        af[m][s] = *(const bf16x8*)&As[row * 64 + (((s * 4 + lg) ^ (row & 7)) << 3)];
    }
#pragma unroll
    for (int n = 0; n < 4; ++n) {
      int row = wc * 64 + n * 16 + lr;
#pragma unroll
      for (int s = 0; s < 2; ++s)
        bfr[n][s] = *(const bf16x8*)&Bs[row * 64 + (((s * 4 + lg) ^ (row & 7)) << 3)];
    }
#pragma unroll
    for (int s = 0; s < 2; ++s)
#pragma unroll
      for (int m = 0; m < MR; ++m)
#pragma unroll
        for (int n = 0; n < 4; ++n)
          acc[m][n] =
              __builtin_amdgcn_mfma_f32_16x16x32_bf16(af[m][s], bfr[n][s], acc[m][n], 0, 0, 0);
  }
#pragma unroll
  for (int n = 0; n < 4; ++n) {
    int col = bcol + wc * 64 + n * 16 + lr;
    float bv = bias[col];
#pragma unroll
    for (int m = 0; m < MR; ++m) {
      int row0 = brow + wr * (BM / 2) + m * 16 + lg * 4;
#pragma unroll
      for (int r = 0; r < 4; ++r) {
        size_t idx = (size_t)(row0 + r) * N + col;
        float v = acc[m][n][r] + bv;
        if (MODE == 0) {
          ((unsigned short*)outp)[idx] = f2b(v);
        } else if (MODE == 1) {
          ((float*)outp)[idx] = v + res[idx];
        } else if (MODE == 2) {
          ((unsigned short*)outp)[idx] = f2b(0.5f * v * (1.f + erff(v * 0.70710678f)));
        } else {
          ((float*)outp)[idx] = v + res[idx];
        }
      }
    }
  }
}

// ---------------- fused attention main: KV-split x2, partial outputs ----------
// grid 1536 = 24 bh x 32 qtiles x 2 halves (XCD-chunked 8x192). Block: 4 waves
// x 32 q rows, 2048 keys (32 iters of KVBLK=64). Structure = R4 (S^T=K@Q^T,
// O^T=V^T@P^T, per-lane softmax in exp2 domain, defer-max THR=11,
// cvt_pk+permlane32_swap, tr_b16 PV, gll16 staging w/ pre-swizzled source).
// Emits unnormalized O^T (f32) + per-q (m,l) partials for the merge pass.
__global__ __launch_bounds__(256, 4) void k_attn(const unsigned short* __restrict__ qkv,
                                                 f32x4* __restrict__ Opart,
                                                 float* __restrict__ ml) {
  __shared__ unsigned short Ks[2][64 * 64];      // [buf][key][hd-grp ^ (key&7)]
  __shared__ unsigned short Vs[2][4 * 64 * 16];  // [buf][hb][key][c]
  const int tid = threadIdx.x;
  const int w = tid >> 6, l = tid & 63;
  const int lq = l & 31, hi = l >> 5;
  // XCD-chunked bijective swizzle: 1536 = 8 * 192
  const int p = blockIdx.x;
  const int linear = (p & 7) * 192 + (p >> 3);
  const int bh = linear >> 6, rem = linear & 63;
  const int qt = rem >> 1, half = rem & 1;
  const int b = bh / 12, h = bh % 12;
  const size_t base = (size_t)b * 4096 * 2304;
  const int qbase = qt * 128 + w * 32;
  const int kv0 = half * 2048;

  // Q as B-frag of S^T (col=q=lq, k: hd = s*16 + hi*8 + j), pre-scaled
  const float SC = 0.18033688f;  // 0.125 * log2(e)
  bf16x8 qb[4];
#pragma unroll
  for (int s = 0; s < 4; ++s) {
    u16x8 raw = *(const u16x8*)(qkv + base + (size_t)(qbase + lq) * 2304 + h * 64 +
                                s * 16 + hi * 8);
    u32x4 pk;
#pragma unroll
    for (int d = 0; d < 4; ++d) {
      float f0 = __builtin_bit_cast(float, (unsigned int)raw[2 * d] << 16) * SC;
      float f1 = __builtin_bit_cast(float, (unsigned int)raw[2 * d + 1] << 16) * SC;
      pk[d] = cvtpk(f0, f1);
    }
    qb[s] = __builtin_bit_cast(bf16x8, pk);
  }

  // per-lane gll16 sources (K col-group pre-swizzled; V subtiled linear)
  const unsigned short* pK = qkv + base + (size_t)(kv0 + 16 * w + (l >> 3)) * 2304 + 768 +
                             h * 64 + (((l & 7) ^ ((l >> 3) & 7)) << 3);
  const unsigned short* pV = qkv + base + (size_t)(kv0 + (l >> 1)) * 2304 + 1536 + h * 64 +
                             w * 16 + ((l & 1) << 3);
  const size_t STEP = (size_t)64 * 2304;

  {
    const char* dK = (const char*)&Ks[0][0] + w * 2048;
    const char* dV = (const char*)&Vs[0][0] + w * 2048;
    gll16(pK, dK);
    gll16(pK + 8 * 2304, dK + 1024);
    gll16(pV, dV);
    gll16(pV + 32 * 2304, dV + 1024);
    pK += STEP;
    pV += STEP;
  }

  f32x16 O[2] = {};  // O^T tiles (hb): col=q=lq, row=hd
  float mrun = -1e30f, lrun = 0.f;

  int it = 0;
  for (int t = 0; t < 32; ++t, it ^= 1) {
    asm volatile("s_waitcnt vmcnt(0)" ::: "memory");
    __syncthreads();
    if (t < 31) {
      const char* dK = (const char*)&Ks[it ^ 1][0] + w * 2048;
      const char* dV = (const char*)&Vs[it ^ 1][0] + w * 2048;
      gll16(pK, dK);
      gll16(pK + 8 * 2304, dK + 1024);
      gll16(pV, dV);
      gll16(pV + 32 * 2304, dV + 1024);
      pK += STEP;
      pV += STEP;
    }

    // S^T = K @ Q^T : two 32x32 tiles (kt), 4 k-steps each
    f32x16 st[2] = {{0}, {0}};
    __builtin_amdgcn_s_setprio(1);
#pragma unroll
    for (int kt = 0; kt < 2; ++kt) {
      int key = kt * 32 + lq;
#pragma unroll
      for (int s = 0; s < 4; ++s) {
        bf16x8 ka =
            *(const bf16x8*)&Ks[it][key * 64 + ((s * 16 + hi * 8) ^ ((key & 7) << 3))];
        st[kt] = __builtin_amdgcn_mfma_f32_32x32x16_bf16(ka, qb[s], st[kt], 0, 0, 0);
      }
    }
    __builtin_amdgcn_s_setprio(0);

    // ---- softmax (per-lane, q = lq) ----
    float pmax = st[0][0];
#pragma unroll
    for (int kt = 0; kt < 2; ++kt)
#pragma unroll
      for (int r = (kt == 0 ? 1 : 0); r < 16; ++r) pmax = fmaxf(pmax, st[kt][r]);
    pmax = fmaxf(pmax, __shfl_xor(pmax, 32));
    if (!__all(pmax - mrun <= 11.0f)) {  // defer-max (2^11 headroom)
      float mnew = fmaxf(mrun, pmax);
      float al = exp2a(mrun - mnew);
      lrun *= al;
#pragma unroll
      for (int hb = 0; hb < 2; ++hb)
#pragma unroll
        for (int r = 0; r < 16; ++r) O[hb][r] *= al;
      mrun = mnew;
    }
    float s0 = 0.f;
#pragma unroll
    for (int kt = 0; kt < 2; ++kt)
#pragma unroll
      for (int r = 0; r < 16; ++r) {
        float pv = exp2a(st[kt][r] - mrun);
        st[kt][r] = pv;
        s0 += pv;
      }
    lrun += s0 + __shfl_xor(s0, 32);

    // ---- P -> B-frags of P^T (col=q): cvt_pk + permlane32_swap ----
    u32x4 pf[4];
#pragma unroll
    for (int kt = 0; kt < 2; ++kt)
#pragma unroll
      for (int h2 = 0; h2 < 2; ++h2) {
        int r0 = h2 * 8;
        unsigned int a0 = cvtpk(st[kt][r0 + 0], st[kt][r0 + 1]);
        unsigned int a1 = cvtpk(st[kt][r0 + 2], st[kt][r0 + 3]);
        unsigned int b0 = cvtpk(st[kt][r0 + 4], st[kt][r0 + 5]);
        unsigned int b1 = cvtpk(st[kt][r0 + 6], st[kt][r0 + 7]);
        swap32(a0, b0);
        swap32(a1, b1);
        pf[kt * 2 + h2] = u32x4{a0, a1, b0, b1};
      }

    // ---- PV: O^T += V^T @ P^T ----
#pragma unroll
    for (int hb = 0; hb < 2; ++hb) {
      u32x2 vt[4][2];
      const unsigned short* vbase = &Vs[it][(hb * 2 + (lq >> 4)) * 1024 + (lq & 15)];
#pragma unroll
      for (int s = 0; s < 4; ++s)
#pragma unroll
        for (int t2 = 0; t2 < 2; ++t2)
          vt[s][t2] = tr_b16(vbase + ((s * 16 + hi * 8 + t2 * 4) << 4));
      asm volatile("s_waitcnt lgkmcnt(0)" ::: "memory");
      __builtin_amdgcn_sched_barrier(0);
      __builtin_amdgcn_s_setprio(1);
#pragma unroll
      for (int s = 0; s < 4; ++s) {
        u32x4 vv = {vt[s][0].x, vt[s][0].y, vt[s][1].x, vt[s][1].y};
        O[hb] = __builtin_amdgcn_mfma_f32_32x32x16_bf16(
            __builtin_bit_cast(bf16x8, vv), __builtin_bit_cast(bf16x8, pf[s]), O[hb], 0, 0, 0);
      }
      __builtin_amdgcn_s_setprio(0);
    }
  }

  // ---- epilogue: write partials (unnormalized O, m, l) ----
  if (hi == 0) {
    ml[((linear * 4 + w) * 2 + 0) * 32 + lq] = mrun;
    ml[((linear * 4 + w) * 2 + 1) * 32 + lq] = lrun;
  }
#pragma unroll
  for (int hb = 0; hb < 2; ++hb)
#pragma unroll
    for (int g = 0; g < 4; ++g) {
      int k = hb * 4 + g;
      f32x4 v = {O[hb][4 * g + 0], O[hb][4 * g + 1], O[hb][4 * g + 2], O[hb][4 * g + 3]};
      Opart[((linear * 4 + w) * 8 + k) * 64 + l] = v;  // lane-contiguous 16B
    }
}

// ---------------- attention merge: combine 2 KV-halves, normalize, bf16 ------
__global__ __launch_bounds__(256) void k_merge(const f32x4* __restrict__ Opart,
                                               const float* __restrict__ ml,
                                               unsigned short* __restrict__ out) {
  const int g = blockIdx.x;  // 768 = 24 bh * 32 qt
  const int bh = g >> 5, qt = g & 31;
  const int b = bh / 12, h = bh % 12;
  const int tid = threadIdx.x;
  const int w = tid >> 6, l = tid & 63;
  const int lq = l & 31, hi = l >> 5;
  const int bidA = bh * 64 + qt * 2;  // half 0
  const int bidB = bidA + 1;          // half 1
  float m0 = ml[((bidA * 4 + w) * 2 + 0) * 32 + lq];
  float l0 = ml[((bidA * 4 + w) * 2 + 1) * 32 + lq];
  float m1 = ml[((bidB * 4 + w) * 2 + 0) * 32 + lq];
  float l1 = ml[((bidB * 4 + w) * 2 + 1) * 32 + lq];
  float m = fmaxf(m0, m1);
  float w0 = exp2a(m0 - m), w1 = exp2a(m1 - m);
  float rl = 1.f / (l0 * w0 + l1 * w1);
  float a0 = w0 * rl, a1 = w1 * rl;
  const int t = qt * 128 + w * 32 + lq;
  unsigned short* orow = out + (size_t)(b * 4096 + t) * 768 + h * 64;
#pragma unroll
  for (int hb = 0; hb < 2; ++hb)
#pragma unroll
    for (int gg = 0; gg < 4; ++gg) {
      int k = hb * 4 + gg;
      f32x4 va = Opart[((bidA * 4 + w) * 8 + k) * 64 + l];
      f32x4 vb = Opart[((bidB * 4 + w) * 8 + k) * 64 + l];
      f32x4 v = va * a0 + vb * a1;
      unsigned int d0 = cvtpk(v[0], v[1]);
      unsigned int d1 = cvtpk(v[2], v[3]);
      *(u32x2*)(orow + hb * 32 + 8 * gg + 4 * hi) = u32x2{d0, d1};
    }
}

// ---------------- launch ----------------
extern "C" void kernel_launch(void* const* d_in, const int* in_sizes, int n_in,
                              void* d_out, int out_size, void* d_ws, size_t ws_size,
                              hipStream_t stream) {
  const float* x = (const float*)d_in[0];
  const float* Wqkv = (const float*)d_in[1];
  const float* bqkv = (const float*)d_in[2];
  const float* Wproj = (const float*)d_in[3];
  const float* bproj = (const float*)d_in[4];
  const float* W1 = (const float*)d_in[5];
  const float* b1 = (const float*)d_in[6];
  const float* W2 = (const float*)d_in[7];
  const float* b2 = (const float*)d_in[8];
  const float* g1 = (const float*)d_in[9];
  const float* be1 = (const float*)d_in[10];
  const float* g2 = (const float*)d_in[11];
  const float* be2 = (const float*)d_in[12];

  char* ws = (char*)d_ws;
  unsigned short* wqkv = (unsigned short*)(ws + 0);
  unsigned short* wproj = (unsigned short*)(ws + 3538944);
  unsigned short* ww1 = (unsigned short*)(ws + 4718592);
  unsigned short* ww2 = (unsigned short*)(ws + 9437184);
  unsigned short* h1 = (unsigned short*)(ws + 14155776);     // 12.6MB; dead after QKV
  unsigned short* qkvb = (unsigned short*)(ws + 26738688);
  unsigned short* attno = (unsigned short*)(ws + 64487424);
  float* x1 = (float*)(ws + 77070336);
  unsigned short* h2 = (unsigned short*)(ws + 102236160);
  unsigned short* m1 = (unsigned short*)(ws + 114819072);    // 50.3MB; written by MLP1
  // attn partials live in dead regions: Opart -> m1 space (exactly 50,331,648B),
  // ml -> h1 space (1.57MB; h1 dead once QKV GEMM has consumed it)
  f32x4* Opart = (f32x4*)m1;
  float* mlbuf = (float*)h1;

  k_cvt_bf16<<<1728, 256, 0, stream>>>(Wqkv, wqkv, 442368);
  k_cvt_bf16<<<576, 256, 0, stream>>>(Wproj, wproj, 147456);
  k_cvt_bf16<<<2304, 256, 0, stream>>>(W1, ww1, 589824);
  k_cvt_bf16<<<2304, 256, 0, stream>>>(W2, ww2, 589824);

  k_ln<<<8192, 64, 0, stream>>>(x, g1, be1, h1);
  k_gemm<0, 128><<<dim3(18, 64), 256, 0, stream>>>(h1, wqkv, bqkv, nullptr, qkvb, 2304, 768);
  k_attn<<<1536, 256, 0, stream>>>(qkvb, Opart, mlbuf);
  k_merge<<<768, 256, 0, stream>>>(Opart, mlbuf, attno);
  k_gemm<1, 64><<<dim3(6, 128), 256, 0, stream>>>(attno, wproj, bproj, x, x1, 768, 768);
  k_ln<<<8192, 64, 0, stream>>>(x1, g2, be2, h2);
  k_gemm<2, 128><<<dim3(24, 64), 256, 0, stream>>>(h2, ww1, b1, nullptr, m1, 3072, 768);
  k_gemm<3, 64><<<dim3(6, 128), 256, 0, stream>>>(m1, ww2, b2, x1, (float*)d_out, 768, 3072);
}